// Round 12
// baseline (202.021 us; speedup 1.0000x reference)
//
#include <hip/hip_runtime.h>
#include <stdint.h>

typedef unsigned short u16;
typedef unsigned int u32;
typedef __bf16 bf16_t;
typedef __bf16 bf16x4 __attribute__((ext_vector_type(4)));
typedef __bf16 bf16x8 __attribute__((ext_vector_type(8)));
typedef float f32x4 __attribute__((ext_vector_type(4)));
typedef float f32x16 __attribute__((ext_vector_type(16)));

#define LOG2E 1.4426950408889634f
#define MFMA32(a, b, c) __builtin_amdgcn_mfma_f32_32x32x16_bf16(a, b, c, 0, 0, 0)

__device__ __forceinline__ u16 f2bf(float f) {
    union { float f; unsigned int u; } v; v.f = f;
    unsigned int r = v.u + 0x7fffu + ((v.u >> 16) & 1u);
    return (u16)(r >> 16);
}

__device__ __forceinline__ bf16x8 ld8f_bf(const float* __restrict__ p) {
    float4 a = *reinterpret_cast<const float4*>(p);
    float4 b = *reinterpret_cast<const float4*>(p + 4);
    bf16x8 r;
    r[0] = (bf16_t)a.x; r[1] = (bf16_t)a.y; r[2] = (bf16_t)a.z; r[3] = (bf16_t)a.w;
    r[4] = (bf16_t)b.x; r[5] = (bf16_t)b.y; r[6] = (bf16_t)b.z; r[7] = (bf16_t)b.w;
    return r;
}

__device__ __forceinline__ u32 cvt_pk_bf16(float a, float b) {
    u32 r;
    asm("v_cvt_pk_bf16_f32 %0, %1, %2" : "=v"(r) : "v"(a), "v"(b));
    return r;
}

__device__ __forceinline__ void plane32_swap(u32& a, u32& b) {
    asm("v_permlane32_swap_b32 %0, %1" : "+v"(a), "+v"(b));
}

// Build PV B-operand fragment (16 keys) from 8 consecutive QK C-regs.
__device__ __forceinline__ bf16x8 pack8(const float* p) {
    u32 c0 = cvt_pk_bf16(p[0], p[1]);
    u32 c1 = cvt_pk_bf16(p[2], p[3]);
    u32 c2 = cvt_pk_bf16(p[4], p[5]);
    u32 c3 = cvt_pk_bf16(p[6], p[7]);
    plane32_swap(c0, c2);
    plane32_swap(c1, c3);
    union { u32 u[4]; bf16x8 v; } f;
    f.u[0] = c0; f.u[1] = c1; f.u[2] = c2; f.u[3] = c3;
    return f.v;
}

// async global->LDS, 16B per lane; LDS dest wave-uniform base + lane*16
__device__ __forceinline__ void g2lds16(const u16* g, u16* l) {
    __builtin_amdgcn_global_load_lds(
        (const __attribute__((address_space(1))) unsigned int*)g,
        (__attribute__((address_space(3))) unsigned int*)l, 16, 0, 0);
}

// ---------------------------------------------------------------------------
// Kernel 1: x[B,C,N] fp32 -> xT[B,N,C] bf16, PRE-SWIZZLED per 16B granule:
// row n, granule g stored at granule slot g^(n&7). Blocks >= 2048 convert
// weights to bf16: wqkb = [64 rows (Wq||Wk)][32 granules swizzled g^(n&7)],
// wvb = 8 slices x 1024 granules (slot d holds Wv[d>>2][slice*32+((d&3)^((d>>2)&3))*8..]).
// ---------------------------------------------------------------------------
__global__ __launch_bounds__(256) void k_transpose(
    const float* __restrict__ x,
    const float* __restrict__ Wq, const float* __restrict__ Wk,
    const float* __restrict__ Wv,
    u16* __restrict__ xT, u16* __restrict__ wqkb, u16* __restrict__ wvb) {
    int blk = blockIdx.x;
    int t = threadIdx.x;
    if (blk >= 2048) {
        if (blk == 2048) {          // Wq||Wk -> wqkb (2048 granules)
            for (int j = 0; j < 8; ++j) {
                int fg = j * 256 + t;
                int n = fg >> 5, g = fg & 31;
                const float* src = (n < 32) ? (Wq + (size_t)n * 256 + g * 8)
                                            : (Wk + (size_t)(n - 32) * 256 + g * 8);
                *reinterpret_cast<bf16x8*>(wqkb + n * 256 + ((g ^ (n & 7)) << 3)) =
                    ld8f_bf(src);
            }
        } else {                    // Wv -> wvb (8192 granules, blocks 2049..2052)
            int base = (blk - 2049) * 2048;
            for (int j = 0; j < 8; ++j) {
                int fg = base + j * 256 + t;
                int slice = fg >> 10, d = fg & 1023;
                int co = d >> 2, g2 = (d & 3) ^ (co & 3);
                *reinterpret_cast<bf16x8*>(wvb + fg * 8) =
                    ld8f_bf(Wv + (size_t)co * 256 + slice * 32 + g2 * 8);
            }
        }
        return;
    }
    __shared__ u16 tile[64][68];
    int b = blk >> 8;
    int r = blk & 255;
    int c0 = (r & 3) * 64;
    int n0 = (r >> 2) * 64;
    const float* xb = x + (size_t)b * 256 * 4096;
    u16* xTb = xT + (size_t)b * 4096 * 256;
    int lc = t >> 4;
    int l4 = (t & 15) * 4;
    #pragma unroll
    for (int p = 0; p < 4; ++p) {
        int c = lc + p * 16;
        float4 v = *reinterpret_cast<const float4*>(xb + (size_t)(c0 + c) * 4096 + n0 + l4);
        tile[c][l4 + 0] = f2bf(v.x); tile[c][l4 + 1] = f2bf(v.y);
        tile[c][l4 + 2] = f2bf(v.z); tile[c][l4 + 3] = f2bf(v.w);
    }
    __syncthreads();
    #pragma unroll
    for (int p = 0; p < 4; ++p) {
        int n = lc + p * 16;
        ushort4 v;
        v.x = tile[l4 + 0][n]; v.y = tile[l4 + 1][n];
        v.z = tile[l4 + 2][n]; v.w = tile[l4 + 3][n];
        int gslot = ((c0 + l4) >> 3) ^ ((n0 + n) & 7);
        *reinterpret_cast<ushort4*>(
            xTb + (size_t)(n0 + n) * 256 + (gslot << 3) + (l4 & 7)) = v;
    }
}

// ---------------------------------------------------------------------------
// Kernel 2 (v14, kept): mega-block proj + double-buffered Wvs, one barrier
// per c-step. 256 blocks x 512 threads, LDS 128 KB, 1 block/CU.
// ---------------------------------------------------------------------------
__global__ __launch_bounds__(512, 2) void k_proj(
    const u16* __restrict__ xT, const u16* __restrict__ wqkb,
    const u16* __restrict__ wvb,
    const float* __restrict__ bq, const float* __restrict__ bk,
    const float* __restrict__ bv,
    u16* __restrict__ qt, u16* __restrict__ kt, u16* __restrict__ vt) {
    __shared__ u16 Xs[128 * 256];
    __shared__ u16 Ws[64 * 256];
    __shared__ u16 Wvs[2][256 * 32];
    int blk = blockIdx.x;
    int b = blk & 7;
    int n0 = (blk >> 3) * 128;
    int t = threadIdx.x;
    int w = t >> 6;
    int lane = t & 63;
    int lo = lane & 15;
    int q = lane >> 4;
    const u16* xTb = xT + (size_t)b * 4096 * 256;

    #pragma unroll
    for (int p = 0; p < 8; ++p)
        g2lds16(xTb + (size_t)n0 * 256 + (p * 512 + t) * 8, &Xs[(p * 512 + w * 64) * 8]);
    #pragma unroll
    for (int p = 0; p < 4; ++p)
        g2lds16(wqkb + (p * 512 + t) * 8, &Ws[(p * 512 + w * 64) * 8]);
    #pragma unroll
    for (int p = 0; p < 2; ++p)
        g2lds16(wvb + (p * 512 + t) * 8, &Wvs[0][(p * 512 + w * 64) * 8]);

    f32x4 accqk[4] = {};
    f32x4 accv[16];
    #pragma unroll
    for (int i = 0; i < 16; ++i) accv[i] = f32x4{0.f, 0.f, 0.f, 0.f};

    int rowA = w * 16 + lo;
    int cw = (w & 3) * 64;
    int nh = (w >> 2) * 64;
    __syncthreads();   // all staging done (drains vmcnt)

    for (int s = 0; s < 8; ++s) {
        int c0 = s * 32;
        const u16* Wv_r = &Wvs[s & 1][0];
        u16* Wv_w = &Wvs[(s + 1) & 1][0];
        if (s < 7) {
            #pragma unroll
            for (int p = 0; p < 2; ++p)
                g2lds16(wvb + (size_t)(s + 1) * 8192 + (p * 512 + t) * 8,
                        Wv_w + (p * 512 + w * 64) * 8);
        }
        int K = c0 >> 3;
        bf16x8 a = *reinterpret_cast<const bf16x8*>(
            &Xs[(rowA * 32 + ((K + q) ^ (lo & 7))) * 8]);
        #pragma unroll
        for (int ot = 0; ot < 4; ++ot) {
            bf16x8 bb = *reinterpret_cast<const bf16x8*>(
                &Ws[((ot * 16 + lo) * 32 + ((K + q) ^ (lo & 7))) * 8]);
            accqk[ot] = __builtin_amdgcn_mfma_f32_16x16x32_bf16(a, bb, accqk[ot], 0, 0, 0);
        }
        bf16x8 xbf[4];
        #pragma unroll
        for (int nt = 0; nt < 4; ++nt)
            xbf[nt] = *reinterpret_cast<const bf16x8*>(
                &Xs[((nh + nt * 16 + lo) * 32 + ((K + q) ^ (lo & 7))) * 8]);
        #pragma unroll
        for (int ct = 0; ct < 4; ++ct) {
            int co = cw + ct * 16 + lo;
            bf16x8 av = *reinterpret_cast<const bf16x8*>(
                Wv_r + (co * 4 + (q ^ (co & 3))) * 8);
            #pragma unroll
            for (int nt = 0; nt < 4; ++nt)
                accv[ct * 4 + nt] = __builtin_amdgcn_mfma_f32_16x16x32_bf16(
                    av, xbf[nt], accv[ct * 4 + nt], 0, 0, 0);
        }
        __syncthreads();   // staging into Wv_w complete; reads of Wv_r done
    }
    #pragma unroll
    for (int ot = 0; ot < 4; ++ot) {
        float bias = (ot < 2) ? bq[ot * 16 + lo] : bk[(ot - 2) * 16 + lo];
        #pragma unroll
        for (int r = 0; r < 4; ++r) {
            int n = n0 + w * 16 + q * 4 + r;
            float val = accqk[ot][r] + bias;
            if (ot < 2) qt[((size_t)b * 4096 + n) * 32 + ot * 16 + lo] = f2bf(val * LOG2E);
            else        kt[((size_t)b * 4096 + n) * 32 + (ot - 2) * 16 + lo] = f2bf(val);
        }
    }
    #pragma unroll
    for (int ct = 0; ct < 4; ++ct) {
        #pragma unroll
        for (int nt = 0; nt < 4; ++nt) {
            int nt_g = ((n0 + nh) >> 4) + nt;
            #pragma unroll
            for (int r = 0; r < 4; ++r) {
                int co = cw + ct * 16 + q * 4 + r;
                float val = accv[ct * 4 + nt][r] + bv[co];
                vt[(((size_t)b * 256 + nt_g) * 256 + co) * 16 + lo] = f2bf(val);
            }
        }
    }
}

// ---------------------------------------------------------------------------
// Kernel 3 (v15): superstep-128 flash. Two independent 64-key sub-bodies per
// barrier (32 barriers total, was 64). LDS: Vs 2x32K + Ks 2x8K = 80 KB ->
// still 2 blocks/CU, so register budget up to 256 is free (lb(256,2) keeps
// the cap at 256 -> spill-impossible). Sub-bodies share only O/lsum
// accumulators -> compiler can co-schedule two full QK->exp->PV chains.
// ---------------------------------------------------------------------------
#define SUBBODY(KB_, VB_)                                                      \
    {                                                                          \
        bf16x8 kf00 = *reinterpret_cast<const bf16x8*>(KB_ + 0 * 512 + gslot8);\
        bf16x8 kf01 = *reinterpret_cast<const bf16x8*>(KB_ + 1 * 512 + gslot8);\
        bf16x8 kf10 = *reinterpret_cast<const bf16x8*>(KB_ + 2 * 512 + gslot8);\
        bf16x8 kf11 = *reinterpret_cast<const bf16x8*>(KB_ + 3 * 512 + gslot8);\
        f32x16 S0 = MFMA32(kf00, qf0, z16);                                    \
        S0 = MFMA32(kf01, qf1, S0);                                            \
        f32x16 S1 = MFMA32(kf10, qf0, z16);                                    \
        S1 = MFMA32(kf11, qf1, S1);                                            \
        float p0[16];                                                          \
        _Pragma("unroll")                                                      \
        for (int i = 0; i < 16; ++i) {                                         \
            p0[i] = __builtin_amdgcn_exp2f(S0[i]);                             \
            lsum += p0[i];                                                     \
        }                                                                      \
        bf16x8 fA = pack8(p0);                                                 \
        bf16x8 fB = pack8(p0 + 8);                                             \
        {                                                                      \
            bf16x8 v0 = *reinterpret_cast<const bf16x8*>(VB_ + 0 * 512 + gslot8);  \
            bf16x8 v1 = *reinterpret_cast<const bf16x8*>(VB_ + 1 * 512 + gslot8);  \
            bf16x8 v2 = *reinterpret_cast<const bf16x8*>(VB_ + 2 * 512 + gslot8);  \
            bf16x8 v3 = *reinterpret_cast<const bf16x8*>(VB_ + 3 * 512 + gslot8);  \
            O0 = MFMA32(v0, fA, O0);                                           \
            O1 = MFMA32(v1, fA, O1);                                           \
            O2 = MFMA32(v2, fA, O2);                                           \
            O3 = MFMA32(v3, fA, O3);                                           \
            bf16x8 v4 = *reinterpret_cast<const bf16x8*>(VB_ + 4 * 512 + gslot8);  \
            bf16x8 v5 = *reinterpret_cast<const bf16x8*>(VB_ + 5 * 512 + gslot8);  \
            bf16x8 v6 = *reinterpret_cast<const bf16x8*>(VB_ + 6 * 512 + gslot8);  \
            bf16x8 v7 = *reinterpret_cast<const bf16x8*>(VB_ + 7 * 512 + gslot8);  \
            O0 = MFMA32(v4, fB, O0);                                           \
            O1 = MFMA32(v5, fB, O1);                                           \
            O2 = MFMA32(v6, fB, O2);                                           \
            O3 = MFMA32(v7, fB, O3);                                           \
        }                                                                      \
        float p1[16];                                                          \
        _Pragma("unroll")                                                      \
        for (int i = 0; i < 16; ++i) {                                         \
            p1[i] = __builtin_amdgcn_exp2f(S1[i]);                             \
            lsum += p1[i];                                                     \
        }                                                                      \
        bf16x8 fC = pack8(p1);                                                 \
        bf16x8 fD = pack8(p1 + 8);                                             \
        {                                                                      \
            bf16x8 v0 = *reinterpret_cast<const bf16x8*>(VB_ + 8 * 512 + gslot8);  \
            bf16x8 v1 = *reinterpret_cast<const bf16x8*>(VB_ + 9 * 512 + gslot8);  \
            bf16x8 v2 = *reinterpret_cast<const bf16x8*>(VB_ + 10 * 512 + gslot8); \
            bf16x8 v3 = *reinterpret_cast<const bf16x8*>(VB_ + 11 * 512 + gslot8); \
            O0 = MFMA32(v0, fC, O0);                                           \
            O1 = MFMA32(v1, fC, O1);                                           \
            O2 = MFMA32(v2, fC, O2);                                           \
            O3 = MFMA32(v3, fC, O3);                                           \
            bf16x8 v4 = *reinterpret_cast<const bf16x8*>(VB_ + 12 * 512 + gslot8); \
            bf16x8 v5 = *reinterpret_cast<const bf16x8*>(VB_ + 13 * 512 + gslot8); \
            bf16x8 v6 = *reinterpret_cast<const bf16x8*>(VB_ + 14 * 512 + gslot8); \
            bf16x8 v7 = *reinterpret_cast<const bf16x8*>(VB_ + 15 * 512 + gslot8); \
            O0 = MFMA32(v4, fD, O0);                                           \
            O1 = MFMA32(v5, fD, O1);                                           \
            O2 = MFMA32(v6, fD, O2);                                           \
            O3 = MFMA32(v7, fD, O3);                                           \
        }                                                                      \
    }

__global__ __launch_bounds__(256, 2) void k_flash(
    const u16* __restrict__ qt, const u16* __restrict__ kt,
    const u16* __restrict__ vt, const float* __restrict__ x,
    const float* __restrict__ gamma, float* __restrict__ out) {
    __shared__ u16 Vs[2][16384];  // 32 chunks (kg*4+cg) x 512 u16 = 32 KB/buf
    __shared__ u16 Ks[2][4096];   // 8 chunks x 512 u16 = 8 KB/buf
    int blk = blockIdx.x;
    int b = blk & 7;
    int rest = blk >> 3;
    int m0 = (rest & 31) * 128;
    int ch0 = (rest >> 5) * 128;
    int t = threadIdx.x;
    int w = t >> 6;
    int lane = t & 63;
    int la = lane & 31;
    int hi = lane >> 5;

    const u16* qtb = qt + (size_t)b * 4096 * 32;
    const u16* ktb = kt + (size_t)b * 4096 * 32;
    const u16* vtb = vt + (size_t)b * 256 * 256 * 16;

    int qw0 = m0 + w * 32;
    bf16x8 qf0 = *reinterpret_cast<const bf16x8*>(qtb + (size_t)(qw0 + la) * 32 + hi * 8);
    bf16x8 qf1 = *reinterpret_cast<const bf16x8*>(qtb + (size_t)(qw0 + la) * 32 + 16 + hi * 8);

    int g = la * 2 + hi;
    int gslot8 = (g ^ (g >> 3)) * 8;          // u16 offset of this lane's read slot
    int sg = lane ^ (lane >> 3);              // source granule for staging slot=lane

    // wave w stages: V key-16-groups w and w+4 (4 ch-chunks each),
    //                K chunks w (keys 0-63 part) and w+4 (keys 64-127 part)
    const u16* vsrcA = vtb + ((size_t)w * 256 + ch0) * 16 + sg * 8;
    const u16* vsrcB = vtb + ((size_t)(w + 4) * 256 + ch0) * 16 + sg * 8;
    const u16* ksrcA = ktb + (size_t)((w >> 1) * 32 + (sg >> 1)) * 32 + (w & 1) * 16 + (sg & 1) * 8;
    const u16* ksrcB = ksrcA + 2048;

    // prologue: stage superstep 0 into buffer 0
    {
        u16* vd = &Vs[0][0];
        u16* kd = &Ks[0][0];
        #pragma unroll
        for (int j = 0; j < 4; ++j) {
            g2lds16(vsrcA + j * 512, vd + (w * 4 + j) * 512);
            g2lds16(vsrcB + j * 512, vd + ((w + 4) * 4 + j) * 512);
        }
        g2lds16(ksrcA, kd + w * 512);
        g2lds16(ksrcB, kd + (w + 4) * 512);
        vsrcA += 32768; vsrcB += 32768;
        ksrcA += 4096;  ksrcB += 4096;
    }

    f32x16 O0 = {}, O1 = {}, O2 = {}, O3 = {};
    const f32x16 z16 = {};
    float lsum = 0.f;
    __syncthreads();

    for (int ss = 0; ss < 32; ++ss) {
        const u16* Vc = &Vs[ss & 1][0];
        const u16* Kc = &Ks[ss & 1][0];
        // ---- prefetch superstep ss+1 into other buffer ----
        if (ss < 31) {
            u16* vd = &Vs[(ss + 1) & 1][0];
            u16* kd = &Ks[(ss + 1) & 1][0];
            #pragma unroll
            for (int j = 0; j < 4; ++j) {
                g2lds16(vsrcA + j * 512, vd + (w * 4 + j) * 512);
                g2lds16(vsrcB + j * 512, vd + ((w + 4) * 4 + j) * 512);
            }
            g2lds16(ksrcA, kd + w * 512);
            g2lds16(ksrcB, kd + (w + 4) * 512);
            vsrcA += 32768; vsrcB += 32768;
            ksrcA += 4096;  ksrcB += 4096;
        }
        // ---- two independent 64-key bodies, one barrier ----
        SUBBODY(Kc, Vc)
        SUBBODY((Kc + 2048), (Vc + 8192))
        __syncthreads();
    }

    // row-sum completion: hi halves hold disjoint key subsets for q = la
    lsum += __shfl_xor(lsum, 32, 64);
    float linv = 1.0f / lsum;
    float gm = gamma[0];
    const float* xb = x + (size_t)b * 256 * 4096;
    float* ob = out + (size_t)b * 256 * 4096;
    int m = m0 + w * 32 + la;
    #pragma unroll
    for (int r = 0; r < 16; ++r) {
        int crow = (r & 3) + 8 * (r >> 2) + 4 * hi;
        size_t i0 = (size_t)(ch0 + crow) * 4096 + m;
        ob[i0]             = gm * (O0[r] * linv) + xb[i0];
        ob[i0 + 32 * 4096] = gm * (O1[r] * linv) + xb[i0 + 32 * 4096];
        ob[i0 + 64 * 4096] = gm * (O2[r] * linv) + xb[i0 + 64 * 4096];
        ob[i0 + 96 * 4096] = gm * (O3[r] * linv) + xb[i0 + 96 * 4096];
    }
}

// ---------------------------------------------------------------------------
// fp32 I/O. Internal bf16. Workspace: qt 2 + kt 2 + vt 16 = 20 MiB.
// d_out (32 MiB): xT bf16 16 MiB + wqkb 32 KiB + wvb 128 KiB (dead before
// k_flash writes out).
// ---------------------------------------------------------------------------
extern "C" void kernel_launch(void* const* d_in, const int* in_sizes, int n_in,
                              void* d_out, int out_size, void* d_ws, size_t ws_size,
                              hipStream_t stream) {
    const float* x     = (const float*)d_in[0];
    const float* Wq    = (const float*)d_in[1];
    const float* bq    = (const float*)d_in[2];
    const float* Wk    = (const float*)d_in[3];
    const float* bk    = (const float*)d_in[4];
    const float* Wv    = (const float*)d_in[5];
    const float* bv    = (const float*)d_in[6];
    const float* gamma = (const float*)d_in[7];
    float* out = (float*)d_out;

    char* ws = (char*)d_ws;
    u16* xT   = (u16*)d_out;                      // 16 MiB bf16 scratch in d_out
    u16* wqkb = (u16*)d_out + 8388608;            // 32 KiB
    u16* wvb  = (u16*)d_out + 8388608 + 16384;    // 128 KiB
    u16* qt = (u16*)ws;                           //  2 MiB [B,N,32]
    u16* kt = (u16*)(ws + 2097152);               //  2 MiB [B,N,32]
    u16* vt = (u16*)(ws + 2 * 2097152);           // 16 MiB [B,nt,ch,16]

    k_transpose<<<2053, 256, 0, stream>>>(x, Wq, Wk, Wv, xT, wqkb, wvb);
    k_proj<<<256, 512, 0, stream>>>(xT, wqkb, wvb, bq, bk, bv, qt, kt, vt);
    k_flash<<<512, 256, 0, stream>>>(qt, kt, vt, x, gamma, out);
}